// Round 3
// baseline (265.887 us; speedup 1.0000x reference)
//
#include <hip/hip_runtime.h>
#include <hip/hip_bf16.h>

#define KE_F  332.0636f
#define MAX_M 1024   // padded molecule count (harness M = 1000)
#define BLK   256
#define NBLK  2048   // best measured grid (round 0: 84.2 us)

typedef int   ivec4 __attribute__((ext_vector_type(4)));
typedef float fvec4 __attribute__((ext_vector_type(4)));

__device__ __forceinline__ float softplusf(float x) {
    return logf(1.0f + expf(x));
}

// One block: prefix-scan num_atoms -> mol_starts[M+1]; derived constants into
// params: [0..3]=c_k/sum(c), [4..7]=exponents_k/d, [16..111]=Z^zexp table;
// also zeroes out[0..M) (harness re-poisons d_out to 0xAA each launch).
__global__ void scan_params_kernel(const int* __restrict__ num_atoms, int M,
                                   const float* __restrict__ d_inv,
                                   const float* __restrict__ z_exp_inv,
                                   const float* __restrict__ c_inv,
                                   const float* __restrict__ exp_inv,
                                   int* __restrict__ mol_starts,
                                   float* __restrict__ params,
                                   float* __restrict__ out) {
    __shared__ int buf[MAX_M];
    int t = threadIdx.x;
    buf[t] = (t < M) ? num_atoms[t] : 0;
    __syncthreads();
    for (int off = 1; off < MAX_M; off <<= 1) {   // Hillis-Steele inclusive scan
        int x = (t >= off) ? buf[t - off] : 0;
        __syncthreads();
        buf[t] += x;
        __syncthreads();
    }
    if (t == 0) mol_starts[0] = 0;
    if (t < M) mol_starts[t + 1] = buf[t];
    if (t == 0) {
        float dd = softplusf(d_inv[0]);
        float c0 = softplusf(c_inv[0]), c1 = softplusf(c_inv[1]);
        float c2 = softplusf(c_inv[2]), c3 = softplusf(c_inv[3]);
        float e0 = softplusf(exp_inv[0]), e1 = softplusf(exp_inv[1]);
        float e2 = softplusf(exp_inv[2]), e3 = softplusf(exp_inv[3]);
        float ic = 1.0f / (c0 + c1 + c2 + c3);
        float id = 1.0f / dd;
        params[0] = c0 * ic; params[1] = c1 * ic; params[2] = c2 * ic; params[3] = c3 * ic;
        params[4] = e0 * id; params[5] = e1 * id; params[6] = e2 * id; params[7] = e3 * id;
    }
    if (t < 96) {                                  // z in [1,94): table of Z^zexp
        float zexp = softplusf(z_exp_inv[0]);
        params[16 + t] = __powf((float)t, zexp);
    }
    for (int k = t; k < M; k += MAX_M) out[k] = 0.0f;
}

// Per-atom packing: pack[a] = (x, y, z, encode(mol, Z)) where
// encode = float((mol << 7) | Z)  (exact: < 2^17). mol via binary search on
// mol_starts (clamps to M-1, matching jnp.repeat total_repeat_length pad).
__global__ void pack_kernel(const float* __restrict__ xyz,
                            const int* __restrict__ z,
                            const int* __restrict__ mol_starts, int M, int N,
                            float4* __restrict__ pack) {
    int a = blockIdx.x * blockDim.x + threadIdx.x;
    if (a >= N) return;
    int lo = 0, hi = M;
    while (hi - lo > 1) {
        int mid = (lo + hi) >> 1;
        if (mol_starts[mid] <= a) lo = mid; else hi = mid;
    }
    pack[a] = make_float4(xyz[3 * a + 0], xyz[3 * a + 1], xyz[3 * a + 2],
                          (float)((lo << 7) | z[a]));
}

// Round-0 structure (proven 84 us), batch widened 4 -> 8 edges/iteration.
// Round-1 post-mortem: cross-iteration software pipelining was rescheduled
// away by the compiler (VGPR stayed 64), and halving TLP cost only +5% ->
// limiter is a per-CU memory-request-rate resource (divergent gather path).
// Within-iteration gather batching IS preserved by the compiler (dataflow),
// so this doubles the in-flight divergent gathers per wave (8 -> 16) with
// one clean variable vs round 0.
__global__ __launch_bounds__(BLK) void nr_main_kernel(
    const int* __restrict__ nbrs, const float* __restrict__ offsets,
    const float4* __restrict__ pack,
    const float* __restrict__ params, float* __restrict__ out, int E, int M) {
    __shared__ float sm[MAX_M];
    __shared__ float zp[96];
    for (int t = threadIdx.x; t < MAX_M; t += BLK) sm[t] = 0.0f;
    if (threadIdx.x < 96) zp[threadIdx.x] = params[16 + threadIdx.x];
    __syncthreads();

    const float4 kk = *(const float4*)(params + 0);   // phi coefficients
    const float4 gg = *(const float4*)(params + 4);   // exponent scales (/d folded)

    const int ngroups = E >> 3;                       // 8 edges per group
    const int stride = gridDim.x * BLK;
    const ivec4* nb4 = (const ivec4*)nbrs;            // 4 ivec4 per group
    const fvec4* of4 = (const fvec4*)offsets;         // 6 fvec4 per group

    for (int g = blockIdx.x * BLK + threadIdx.x; g < ngroups; g += stride) {
        // Coalesced streaming loads: 4x int4 (8 edges) + 6x float4 (24 floats).
        const ivec4 n0 = __builtin_nontemporal_load(nb4 + 4 * (size_t)g);
        const ivec4 n1 = __builtin_nontemporal_load(nb4 + 4 * (size_t)g + 1);
        const ivec4 n2 = __builtin_nontemporal_load(nb4 + 4 * (size_t)g + 2);
        const ivec4 n3 = __builtin_nontemporal_load(nb4 + 4 * (size_t)g + 3);
        const fvec4 O0 = __builtin_nontemporal_load(of4 + 6 * (size_t)g);
        const fvec4 O1 = __builtin_nontemporal_load(of4 + 6 * (size_t)g + 1);
        const fvec4 O2 = __builtin_nontemporal_load(of4 + 6 * (size_t)g + 2);
        const fvec4 O3 = __builtin_nontemporal_load(of4 + 6 * (size_t)g + 3);
        const fvec4 O4 = __builtin_nontemporal_load(of4 + 6 * (size_t)g + 4);
        const fvec4 O5 = __builtin_nontemporal_load(of4 + 6 * (size_t)g + 5);

        const int   iv[8] = {n0.x, n0.z, n1.x, n1.z, n2.x, n2.z, n3.x, n3.z};
        const int   jv[8] = {n0.y, n0.w, n1.y, n1.w, n2.y, n2.w, n3.y, n3.w};
        // flat offset o[24]; edge k -> (o[3k], o[3k+1], o[3k+2])
        const float ox[8] = {O0.x, O0.w, O1.z, O2.y, O3.x, O3.w, O4.z, O5.y};
        const float oy[8] = {O0.y, O1.x, O1.w, O2.z, O3.y, O4.x, O4.w, O5.z};
        const float oz[8] = {O0.z, O1.y, O2.x, O2.w, O3.z, O4.y, O5.x, O5.w};

        bool   m[8];
        float4 pi[8], pj[8];
#pragma unroll
        for (int k = 0; k < 8; ++k) {    // issue ALL 16 gathers batched, branch-free
            m[k] = jv[k] > iv[k];
            const int ii = m[k] ? iv[k] : 0;   // masked lanes broadcast line 0
            const int jj = m[k] ? jv[k] : 0;
            pi[k] = pack[ii];
            pj[k] = pack[jj];
        }
#pragma unroll
        for (int k = 0; k < 8; ++k) {
            const float dx = pi[k].x - pj[k].x - ox[k];
            const float dy = pi[k].y - pj[k].y - oy[k];
            const float dz = pi[k].z - pj[k].z - oz[k];
            const float r2 = fmaf(dx, dx, fmaf(dy, dy, dz * dz)) + 3e-15f;
            const bool ok = m[k] && (r2 < 25.0f);
            const int  wi = (int)pi[k].w;
            const int  wj = (int)pj[k].w;
            const float zi = (float)(wi & 127);
            const float zj = (float)(wj & 127);
            const float inv_r = rsqrtf(r2);
            const float r = r2 * inv_r;
            const float S = zp[wi & 127] + zp[wj & 127];
            const float rs = r * S;
            const float phi = kk.x * __expf(-gg.x * rs) + kk.y * __expf(-gg.y * rs) +
                              kk.z * __expf(-gg.z * rs) + kk.w * __expf(-gg.w * rs);
            const float fc = __expf(-__fdividef(r2, 25.0f - r2));
            const float val = KE_F * zi * zj * inv_r * phi * fc;
            if (ok) atomicAdd(&sm[wi >> 7], val);   // inf/nan of masked lanes discarded
        }
    }

    // Tail edges [8*ngroups, E) — scalar path (E%8, empty in harness).
    for (int e = (ngroups << 3) + blockIdx.x * BLK + threadIdx.x; e < E; e += stride) {
        const int i = nbrs[2 * e], j = nbrs[2 * e + 1];
        if (j <= i) continue;
        const float oxs = offsets[3 * e], oys = offsets[3 * e + 1], ozs = offsets[3 * e + 2];
        const float4 pis = pack[i], pjs = pack[j];
        const float dx = pis.x - pjs.x - oxs;
        const float dy = pis.y - pjs.y - oys;
        const float dz = pis.z - pjs.z - ozs;
        const float r2 = fmaf(dx, dx, fmaf(dy, dy, dz * dz)) + 3e-15f;
        if (r2 >= 25.0f) continue;
        const int  wi = (int)pis.w;
        const int  wj = (int)pjs.w;
        const float inv_r = rsqrtf(r2);
        const float r = r2 * inv_r;
        const float S = zp[wi & 127] + zp[wj & 127];
        const float rs = r * S;
        const float phi = kk.x * __expf(-gg.x * rs) + kk.y * __expf(-gg.y * rs) +
                          kk.z * __expf(-gg.z * rs) + kk.w * __expf(-gg.w * rs);
        const float fc = __expf(-__fdividef(r2, 25.0f - r2));
        atomicAdd(&sm[wi >> 7],
                  KE_F * (float)(wi & 127) * (float)(wj & 127) * inv_r * phi * fc);
    }

    __syncthreads();
    // Sparse flush: ~35% of slots nonzero per block -> ~0.7M global atomics total.
    for (int t = threadIdx.x; t < M; t += BLK) {
        const float v = sm[t];
        if (v != 0.0f) atomicAdd(&out[t], v);
    }
}

extern "C" void kernel_launch(void* const* d_in, const int* in_sizes, int n_in,
                              void* d_out, int out_size, void* d_ws, size_t ws_size,
                              hipStream_t stream) {
    const float* xyz       = (const float*)d_in[0];
    const int*   z         = (const int*)d_in[1];
    const int*   nbrs      = (const int*)d_in[2];
    const int*   num_atoms = (const int*)d_in[3];
    const float* offsets   = (const float*)d_in[4];
    const float* d_inv     = (const float*)d_in[5];
    const float* z_exp_inv = (const float*)d_in[6];
    const float* c_inv     = (const float*)d_in[7];
    const float* exp_inv   = (const float*)d_in[8];
    float* out = (float*)d_out;

    const int N = in_sizes[0] / 3;
    const int E = in_sizes[2] / 2;
    const int M = in_sizes[3];

    // Workspace layout (16B-aligned regions):
    //   [0, 4096)            : mol_starts (M+1 ints)
    //   [4096, 8192)         : params (112 floats used)
    //   [8192, 8192+16N)     : pack (N float4; w = (mol<<7)|Z encoded)
    char* w = (char*)d_ws;
    int*    mol_starts = (int*)w;
    float*  params     = (float*)(w + 4096);
    float4* pack       = (float4*)(w + 8192);

    scan_params_kernel<<<1, MAX_M, 0, stream>>>(num_atoms, M, d_inv, z_exp_inv,
                                                c_inv, exp_inv, mol_starts,
                                                params, out);
    pack_kernel<<<(N + BLK - 1) / BLK, BLK, 0, stream>>>(xyz, z, mol_starts, M, N,
                                                         pack);
    nr_main_kernel<<<NBLK, BLK, 0, stream>>>(nbrs, offsets, pack,
                                             params, out, E, M);
}

// Round 4
// 263.944 us; speedup vs baseline: 1.0074x; 1.0074x over previous
//
#include <hip/hip_runtime.h>
#include <hip/hip_bf16.h>

#define KE_F  332.0636f
#define MAX_M 1024   // padded molecule count (harness M = 1000)
#define BLK   256
#define NBLK  2048   // best measured grid (round 0: 84.2 us)
#define CHUNK 512    // edges staged per block-iteration (2 per thread)

typedef int   ivec2 __attribute__((ext_vector_type(2)));
typedef int   ivec4 __attribute__((ext_vector_type(4)));
typedef float fvec4 __attribute__((ext_vector_type(4)));

__device__ __forceinline__ float softplusf(float x) {
    return logf(1.0f + expf(x));
}

// One block: prefix-scan num_atoms -> mol_starts[M+1]; derived constants into
// params: [0..3]=c_k/sum(c), [4..7]=exponents_k/d, [16..111]=Z^zexp table;
// also zeroes out[0..M) (harness re-poisons d_out to 0xAA each launch).
__global__ void scan_params_kernel(const int* __restrict__ num_atoms, int M,
                                   const float* __restrict__ d_inv,
                                   const float* __restrict__ z_exp_inv,
                                   const float* __restrict__ c_inv,
                                   const float* __restrict__ exp_inv,
                                   int* __restrict__ mol_starts,
                                   float* __restrict__ params,
                                   float* __restrict__ out) {
    __shared__ int buf[MAX_M];
    int t = threadIdx.x;
    buf[t] = (t < M) ? num_atoms[t] : 0;
    __syncthreads();
    for (int off = 1; off < MAX_M; off <<= 1) {   // Hillis-Steele inclusive scan
        int x = (t >= off) ? buf[t - off] : 0;
        __syncthreads();
        buf[t] += x;
        __syncthreads();
    }
    if (t == 0) mol_starts[0] = 0;
    if (t < M) mol_starts[t + 1] = buf[t];
    if (t == 0) {
        float dd = softplusf(d_inv[0]);
        float c0 = softplusf(c_inv[0]), c1 = softplusf(c_inv[1]);
        float c2 = softplusf(c_inv[2]), c3 = softplusf(c_inv[3]);
        float e0 = softplusf(exp_inv[0]), e1 = softplusf(exp_inv[1]);
        float e2 = softplusf(exp_inv[2]), e3 = softplusf(exp_inv[3]);
        float ic = 1.0f / (c0 + c1 + c2 + c3);
        float id = 1.0f / dd;
        params[0] = c0 * ic; params[1] = c1 * ic; params[2] = c2 * ic; params[3] = c3 * ic;
        params[4] = e0 * id; params[5] = e1 * id; params[6] = e2 * id; params[7] = e3 * id;
    }
    if (t < 96) {                                  // z in [1,94): table of Z^zexp
        float zexp = softplusf(z_exp_inv[0]);
        params[16 + t] = __powf((float)t, zexp);
    }
    for (int k = t; k < M; k += MAX_M) out[k] = 0.0f;
}

// Per-atom packing: pack[a] = (x, y, z, encode(mol, Z)) where
// encode = float((mol << 7) | Z)  (exact: < 2^17). mol via binary search on
// mol_starts (clamps to M-1, matching jnp.repeat total_repeat_length pad).
__global__ void pack_kernel(const float* __restrict__ xyz,
                            const int* __restrict__ z,
                            const int* __restrict__ mol_starts, int M, int N,
                            float4* __restrict__ pack) {
    int a = blockIdx.x * blockDim.x + threadIdx.x;
    if (a >= N) return;
    int lo = 0, hi = M;
    while (hi - lo > 1) {
        int mid = (lo + hi) >> 1;
        if (mol_starts[mid] <= a) lo = mid; else hi = mid;
    }
    pack[a] = make_float4(xyz[3 * a + 0], xyz[3 * a + 1], xyz[3 * a + 2],
                          (float)((lo << 7) | z[a]));
}

// LDS-staged edge stream. Evidence model (R0/R2/R3 regression): runtime is
// proportional to non-coalescable VMEM line-requests/CU. R0's per-thread
// AoS batching put lanes at 32-48B stride (1-2 lanes per 64B line) -> the
// 160MB edge stream cost ~52 line-requests per 64 edges vs a coalesced
// floor of 20; gathers (~66, random 16B from the 3.2MB pack table) are
// irreducible. Here a block stages 512 edges into LDS with consecutive-lane
// float4 loads (4 lanes/line, every byte used), then threads read their 2
// edges from LDS (8B/12B stride -> <=2-way bank aliasing, free). Gather +
// math code is bitwise-identical to the verified R0 kernel (absmax 0.0).
__global__ __launch_bounds__(BLK) void nr_main_kernel(
    const int* __restrict__ nbrs, const float* __restrict__ offsets,
    const float4* __restrict__ pack,
    const float* __restrict__ params, float* __restrict__ out, int E, int M) {
    __shared__ float sm[MAX_M];
    __shared__ float zp[96];
    __shared__ ivec4 snb[CHUNK / 2];           // 4 KB: CHUNK int2 pairs
    __shared__ fvec4 sof[(CHUNK * 3) / 4];     // 6 KB: CHUNK float3 offsets
    for (int t = threadIdx.x; t < MAX_M; t += BLK) sm[t] = 0.0f;
    if (threadIdx.x < 96) zp[threadIdx.x] = params[16 + threadIdx.x];
    __syncthreads();

    const float4 kk = *(const float4*)(params + 0);   // phi coefficients
    const float4 gg = *(const float4*)(params + 4);   // exponent scales (/d folded)

    const int nchunks = E / CHUNK;
    const ivec4* nb4 = (const ivec4*)nbrs;            // CHUNK/2 ivec4 per chunk
    const fvec4* of4 = (const fvec4*)offsets;         // 3*CHUNK/4 fvec4 per chunk
    const ivec2* snb2 = (const ivec2*)snb;
    const float* sofF = (const float*)sof;

    for (int c = blockIdx.x; c < nchunks; c += gridDim.x) {
        __syncthreads();   // LDS stage buffers reused from previous chunk
        // Stage: perfectly coalesced (lane l -> float4 l), nontemporal.
        snb[threadIdx.x] =
            __builtin_nontemporal_load(nb4 + (size_t)c * (CHUNK / 2) + threadIdx.x);
#pragma unroll
        for (int k = 0; k < 2; ++k) {
            const int idx = threadIdx.x + k * BLK;
            if (idx < (CHUNK * 3) / 4)
                sof[idx] = __builtin_nontemporal_load(
                    of4 + (size_t)c * ((CHUNK * 3) / 4) + idx);
        }
        __syncthreads();

        // Each thread: 2 edges, lane-contiguous within the chunk.
        int   iv[2], jv[2];
        float ox[2], oy[2], oz[2];
        bool  m[2];
        float4 pi[2], pj[2];
#pragma unroll
        for (int h = 0; h < 2; ++h) {
            const int l = threadIdx.x + h * BLK;
            const ivec2 nb = snb2[l];
            iv[h] = nb.x; jv[h] = nb.y;
            ox[h] = sofF[3 * l + 0];
            oy[h] = sofF[3 * l + 1];
            oz[h] = sofF[3 * l + 2];
        }
#pragma unroll
        for (int h = 0; h < 2; ++h) {   // issue ALL 4 gathers batched, branch-free
            m[h] = jv[h] > iv[h];
            const int ii = m[h] ? iv[h] : 0;   // masked lanes broadcast line 0
            const int jj = m[h] ? jv[h] : 0;
            pi[h] = pack[ii];
            pj[h] = pack[jj];
        }
#pragma unroll
        for (int h = 0; h < 2; ++h) {
            const float dx = pi[h].x - pj[h].x - ox[h];
            const float dy = pi[h].y - pj[h].y - oy[h];
            const float dz = pi[h].z - pj[h].z - oz[h];
            const float r2 = fmaf(dx, dx, fmaf(dy, dy, dz * dz)) + 3e-15f;
            const bool ok = m[h] && (r2 < 25.0f);
            const int  wi = (int)pi[h].w;
            const int  wj = (int)pj[h].w;
            const float zi = (float)(wi & 127);
            const float zj = (float)(wj & 127);
            const float inv_r = rsqrtf(r2);
            const float r = r2 * inv_r;
            const float S = zp[wi & 127] + zp[wj & 127];
            const float rs = r * S;
            const float phi = kk.x * __expf(-gg.x * rs) + kk.y * __expf(-gg.y * rs) +
                              kk.z * __expf(-gg.z * rs) + kk.w * __expf(-gg.w * rs);
            const float fc = __expf(-__fdividef(r2, 25.0f - r2));
            const float val = KE_F * zi * zj * inv_r * phi * fc;
            if (ok) atomicAdd(&sm[wi >> 7], val);   // inf/nan of masked lanes discarded
        }
    }

    // Tail edges [nchunks*CHUNK, E) — scalar path (empty in harness: 8M%512==0).
    const int stride = gridDim.x * BLK;
    for (int e = nchunks * CHUNK + blockIdx.x * BLK + threadIdx.x; e < E; e += stride) {
        const int i = nbrs[2 * e], j = nbrs[2 * e + 1];
        if (j <= i) continue;
        const float oxs = offsets[3 * e], oys = offsets[3 * e + 1], ozs = offsets[3 * e + 2];
        const float4 pis = pack[i], pjs = pack[j];
        const float dx = pis.x - pjs.x - oxs;
        const float dy = pis.y - pjs.y - oys;
        const float dz = pis.z - pjs.z - ozs;
        const float r2 = fmaf(dx, dx, fmaf(dy, dy, dz * dz)) + 3e-15f;
        if (r2 >= 25.0f) continue;
        const int  wi = (int)pis.w;
        const int  wj = (int)pjs.w;
        const float inv_r = rsqrtf(r2);
        const float r = r2 * inv_r;
        const float S = zp[wi & 127] + zp[wj & 127];
        const float rs = r * S;
        const float phi = kk.x * __expf(-gg.x * rs) + kk.y * __expf(-gg.y * rs) +
                          kk.z * __expf(-gg.z * rs) + kk.w * __expf(-gg.w * rs);
        const float fc = __expf(-__fdividef(r2, 25.0f - r2));
        atomicAdd(&sm[wi >> 7],
                  KE_F * (float)(wi & 127) * (float)(wj & 127) * inv_r * phi * fc);
    }

    __syncthreads();
    // Sparse flush: ~35% of slots nonzero per block -> ~0.7M global atomics total.
    for (int t = threadIdx.x; t < M; t += BLK) {
        const float v = sm[t];
        if (v != 0.0f) atomicAdd(&out[t], v);
    }
}

extern "C" void kernel_launch(void* const* d_in, const int* in_sizes, int n_in,
                              void* d_out, int out_size, void* d_ws, size_t ws_size,
                              hipStream_t stream) {
    const float* xyz       = (const float*)d_in[0];
    const int*   z         = (const int*)d_in[1];
    const int*   nbrs      = (const int*)d_in[2];
    const int*   num_atoms = (const int*)d_in[3];
    const float* offsets   = (const float*)d_in[4];
    const float* d_inv     = (const float*)d_in[5];
    const float* z_exp_inv = (const float*)d_in[6];
    const float* c_inv     = (const float*)d_in[7];
    const float* exp_inv   = (const float*)d_in[8];
    float* out = (float*)d_out;

    const int N = in_sizes[0] / 3;
    const int E = in_sizes[2] / 2;
    const int M = in_sizes[3];

    // Workspace layout (16B-aligned regions):
    //   [0, 4096)            : mol_starts (M+1 ints)
    //   [4096, 8192)         : params (112 floats used)
    //   [8192, 8192+16N)     : pack (N float4; w = (mol<<7)|Z encoded)
    char* w = (char*)d_ws;
    int*    mol_starts = (int*)w;
    float*  params     = (float*)(w + 4096);
    float4* pack       = (float4*)(w + 8192);

    scan_params_kernel<<<1, MAX_M, 0, stream>>>(num_atoms, M, d_inv, z_exp_inv,
                                                c_inv, exp_inv, mol_starts,
                                                params, out);
    pack_kernel<<<(N + BLK - 1) / BLK, BLK, 0, stream>>>(xyz, z, mol_starts, M, N,
                                                         pack);
    nr_main_kernel<<<NBLK, BLK, 0, stream>>>(nbrs, offsets, pack,
                                             params, out, E, M);
}

// Round 6
// 240.776 us; speedup vs baseline: 1.1043x; 1.0962x over previous
//
#include <hip/hip_runtime.h>
#include <hip/hip_bf16.h>

#define KE_F   332.0636f
#define MAX_M  1024   // padded molecule count (harness M = 1000)
#define BLK    256
#define NBLK   2048   // best measured grid (R0: 84.2 us)
#define WCHUNK 256    // edges per wave-iteration (4 per lane)

typedef int   ivec2 __attribute__((ext_vector_type(2)));
typedef int   ivec4 __attribute__((ext_vector_type(4)));
typedef float fvec4 __attribute__((ext_vector_type(4)));

__device__ __forceinline__ float softplusf(float x) {
    return logf(1.0f + expf(x));
}

// Compile-time fence: no instruction emitted; blocks the scheduler from
// moving LDS/VMEM ops across it (wave-synchronous LDS exchange idiom).
__device__ __forceinline__ void wave_fence() {
    __builtin_amdgcn_wave_barrier();
    asm volatile("" ::: "memory");
}

// One block: prefix-scan num_atoms -> mol_starts[M+1]; derived constants into
// params: [0..3]=c_k/sum(c), [4..7]=exponents_k/d, [16..111]=Z^zexp table;
// also zeroes out[0..M) (harness re-poisons d_out to 0xAA each launch).
__global__ void scan_params_kernel(const int* __restrict__ num_atoms, int M,
                                   const float* __restrict__ d_inv,
                                   const float* __restrict__ z_exp_inv,
                                   const float* __restrict__ c_inv,
                                   const float* __restrict__ exp_inv,
                                   int* __restrict__ mol_starts,
                                   float* __restrict__ params,
                                   float* __restrict__ out) {
    __shared__ int buf[MAX_M];
    int t = threadIdx.x;
    buf[t] = (t < M) ? num_atoms[t] : 0;
    __syncthreads();
    for (int off = 1; off < MAX_M; off <<= 1) {   // Hillis-Steele inclusive scan
        int x = (t >= off) ? buf[t - off] : 0;
        __syncthreads();
        buf[t] += x;
        __syncthreads();
    }
    if (t == 0) mol_starts[0] = 0;
    if (t < M) mol_starts[t + 1] = buf[t];
    if (t == 0) {
        float dd = softplusf(d_inv[0]);
        float c0 = softplusf(c_inv[0]), c1 = softplusf(c_inv[1]);
        float c2 = softplusf(c_inv[2]), c3 = softplusf(c_inv[3]);
        float e0 = softplusf(exp_inv[0]), e1 = softplusf(exp_inv[1]);
        float e2 = softplusf(exp_inv[2]), e3 = softplusf(exp_inv[3]);
        float ic = 1.0f / (c0 + c1 + c2 + c3);
        float id = 1.0f / dd;
        params[0] = c0 * ic; params[1] = c1 * ic; params[2] = c2 * ic; params[3] = c3 * ic;
        params[4] = e0 * id; params[5] = e1 * id; params[6] = e2 * id; params[7] = e3 * id;
    }
    if (t < 96) {                                  // z in [1,94): table of Z^zexp
        float zexp = softplusf(z_exp_inv[0]);
        params[16 + t] = __powf((float)t, zexp);
    }
    for (int k = t; k < M; k += MAX_M) out[k] = 0.0f;
}

// Per-atom packing: pack[a] = (x, y, z, encode(mol, Z)) where
// encode = float((mol << 7) | Z)  (exact: < 2^17). mol via binary search on
// mol_starts (clamps to M-1, matching jnp.repeat total_repeat_length pad).
__global__ void pack_kernel(const float* __restrict__ xyz,
                            const int* __restrict__ z,
                            const int* __restrict__ mol_starts, int M, int N,
                            float4* __restrict__ pack) {
    int a = blockIdx.x * blockDim.x + threadIdx.x;
    if (a >= N) return;
    int lo = 0, hi = M;
    while (hi - lo > 1) {
        int mid = (lo + hi) >> 1;
        if (mol_starts[mid] <= a) lo = mid; else hi = mid;
    }
    pack[a] = make_float4(xyz[3 * a + 0], xyz[3 * a + 1], xyz[3 * a + 2],
                          (float)((lo << 7) | z[a]));
}

// Wave-cooperative SoA edge consumption, barrier-free (R5 design, fences
// fixed). R5's failure: the LDS offset bounce had no compiler-visible
// dependence between the fvec4 ds_writes and the float ds_reads at
// different per-lane indices -> scheduler hoisted reads past writes ->
// garbage offsets. Fix: wave_fence() (zero-instruction scheduling barrier)
// before the writes (WAR vs prev iteration) and after them (RAW for this
// iteration). Same-wave LDS ops execute in order in HW, so no extra
// waitcnt or cross-wave sync is needed; the loop stays barrier-free.
//
// Why this layout (two-floor / miss-throughput model from R0-R4):
//  - consecutive LANES take consecutive edges: nbrs as per-lane int2 ->
//    8 lines per 64 edges (R0 AoS: 16); offsets via 3 coalesced fvec4
//    per 256 edges bounced through WAVE-PRIVATE LDS -> 12 lines per 64
//    edges (R0: ~36). Stream lookups 52 -> 20 per 64 edges.
//  - gathers + math bitwise-identical to R0 (absmax 0.0); all 8 gathers
//    of a lane's 4 edges issued back-to-back BEFORE the LDS-write section
//    so gather issue never waits on the offset-load vmcnt.
__global__ __launch_bounds__(BLK) void nr_main_kernel(
    const int* __restrict__ nbrs, const float* __restrict__ offsets,
    const float4* __restrict__ pack,
    const float* __restrict__ params, float* __restrict__ out, int E, int M) {
    __shared__ float sm[MAX_M];
    __shared__ float zp[96];
    __shared__ float sof[4][WCHUNK * 3];   // 12 KB: per-wave offset bounce
    for (int t = threadIdx.x; t < MAX_M; t += BLK) sm[t] = 0.0f;
    if (threadIdx.x < 96) zp[threadIdx.x] = params[16 + threadIdx.x];
    __syncthreads();

    const float4 kk = *(const float4*)(params + 0);   // phi coefficients
    const float4 gg = *(const float4*)(params + 4);   // exponent scales (/d folded)

    const int lane = threadIdx.x & 63;
    float* myof = sof[threadIdx.x >> 6];              // this wave's private region

    const int nchunks = E / WCHUNK;
    const int gw = (blockIdx.x * BLK + threadIdx.x) >> 6;   // global wave id
    const int nw = (gridDim.x * BLK) >> 6;                  // total waves

    const ivec2* nbp = (const ivec2*)nbrs;
    const fvec4* of4 = (const fvec4*)offsets;

    for (int c = gw; c < nchunks; c += nw) {
        const size_t eb = (size_t)c * WCHUNK;
        // nbrs: per-lane int2, perfectly coalesced (512B/instr).
        ivec2 nb[4];
#pragma unroll
        for (int h = 0; h < 4; ++h)
            nb[h] = __builtin_nontemporal_load(nbp + eb + 64 * h + lane);
        // offsets: 3 coalesced float4 instrs (1024B each), for LDS bounce.
        const fvec4* ofb = of4 + (size_t)c * ((WCHUNK * 3) / 4);
        const fvec4 F0 = __builtin_nontemporal_load(ofb + lane);
        const fvec4 F1 = __builtin_nontemporal_load(ofb + 64 + lane);
        const fvec4 F2 = __builtin_nontemporal_load(ofb + 128 + lane);

        // Issue ALL 8 gathers batched, branch-free (masked lanes -> line 0),
        // before the LDS-write section (no vmcnt dependence on F0-F2).
        bool   m[4];
        float4 pi[4], pj[4];
#pragma unroll
        for (int h = 0; h < 4; ++h) {
            const int iv = nb[h].x, jv = nb[h].y;
            m[h] = jv > iv;
            pi[h] = pack[m[h] ? iv : 0];
            pj[h] = pack[m[h] ? jv : 0];
        }

        wave_fence();   // WAR: prev iteration's LDS reads complete first
        *(fvec4*)&myof[4 * lane]       = F0;   // conflict-free b128 writes;
        *(fvec4*)&myof[4 * lane + 256] = F1;   // myof[f] = offsets[768c+f]
        *(fvec4*)&myof[4 * lane + 512] = F2;
        wave_fence();   // RAW: reads below must not hoist above the writes

#pragma unroll
        for (int h = 0; h < 4; ++h) {
            // lane's edge h = eb + 64h + lane; its floats at 192h+3*lane.
            const float oxv = myof[192 * h + 3 * lane + 0];
            const float oyv = myof[192 * h + 3 * lane + 1];
            const float ozv = myof[192 * h + 3 * lane + 2];
            const float dx = pi[h].x - pj[h].x - oxv;
            const float dy = pi[h].y - pj[h].y - oyv;
            const float dz = pi[h].z - pj[h].z - ozv;
            const float r2 = fmaf(dx, dx, fmaf(dy, dy, dz * dz)) + 3e-15f;
            const bool ok = m[h] && (r2 < 25.0f);
            const int  wi = (int)pi[h].w;
            const int  wj = (int)pj[h].w;
            const float zi = (float)(wi & 127);
            const float zj = (float)(wj & 127);
            const float inv_r = rsqrtf(r2);
            const float r = r2 * inv_r;
            const float S = zp[wi & 127] + zp[wj & 127];
            const float rs = r * S;
            const float phi = kk.x * __expf(-gg.x * rs) + kk.y * __expf(-gg.y * rs) +
                              kk.z * __expf(-gg.z * rs) + kk.w * __expf(-gg.w * rs);
            const float fc = __expf(-__fdividef(r2, 25.0f - r2));
            const float val = KE_F * zi * zj * inv_r * phi * fc;
            if (ok) atomicAdd(&sm[wi >> 7], val);   // inf/nan of masked lanes discarded
        }
    }

    // Tail edges [nchunks*WCHUNK, E) — scalar path (empty in harness).
    const int stride = gridDim.x * BLK;
    for (int e = nchunks * WCHUNK + blockIdx.x * BLK + threadIdx.x; e < E; e += stride) {
        const int i = nbrs[2 * e], j = nbrs[2 * e + 1];
        if (j <= i) continue;
        const float oxs = offsets[3 * e], oys = offsets[3 * e + 1], ozs = offsets[3 * e + 2];
        const float4 pis = pack[i], pjs = pack[j];
        const float dx = pis.x - pjs.x - oxs;
        const float dy = pis.y - pjs.y - oys;
        const float dz = pis.z - pjs.z - ozs;
        const float r2 = fmaf(dx, dx, fmaf(dy, dy, dz * dz)) + 3e-15f;
        if (r2 >= 25.0f) continue;
        const int  wi = (int)pis.w;
        const int  wj = (int)pjs.w;
        const float inv_r = rsqrtf(r2);
        const float r = r2 * inv_r;
        const float S = zp[wi & 127] + zp[wj & 127];
        const float rs = r * S;
        const float phi = kk.x * __expf(-gg.x * rs) + kk.y * __expf(-gg.y * rs) +
                          kk.z * __expf(-gg.z * rs) + kk.w * __expf(-gg.w * rs);
        const float fc = __expf(-__fdividef(r2, 25.0f - r2));
        atomicAdd(&sm[wi >> 7],
                  KE_F * (float)(wi & 127) * (float)(wj & 127) * inv_r * phi * fc);
    }

    __syncthreads();
    // Sparse flush: ~35% of slots nonzero per block -> ~0.7M global atomics total.
    for (int t = threadIdx.x; t < M; t += BLK) {
        const float v = sm[t];
        if (v != 0.0f) atomicAdd(&out[t], v);
    }
}

extern "C" void kernel_launch(void* const* d_in, const int* in_sizes, int n_in,
                              void* d_out, int out_size, void* d_ws, size_t ws_size,
                              hipStream_t stream) {
    const float* xyz       = (const float*)d_in[0];
    const int*   z         = (const int*)d_in[1];
    const int*   nbrs      = (const int*)d_in[2];
    const int*   num_atoms = (const int*)d_in[3];
    const float* offsets   = (const float*)d_in[4];
    const float* d_inv     = (const float*)d_in[5];
    const float* z_exp_inv = (const float*)d_in[6];
    const float* c_inv     = (const float*)d_in[7];
    const float* exp_inv   = (const float*)d_in[8];
    float* out = (float*)d_out;

    const int N = in_sizes[0] / 3;
    const int E = in_sizes[2] / 2;
    const int M = in_sizes[3];

    // Workspace layout (16B-aligned regions):
    //   [0, 4096)            : mol_starts (M+1 ints)
    //   [4096, 8192)         : params (112 floats used)
    //   [8192, 8192+16N)     : pack (N float4; w = (mol<<7)|Z encoded)
    char* w = (char*)d_ws;
    int*    mol_starts = (int*)w;
    float*  params     = (float*)(w + 4096);
    float4* pack       = (float4*)(w + 8192);

    scan_params_kernel<<<1, MAX_M, 0, stream>>>(num_atoms, M, d_inv, z_exp_inv,
                                                c_inv, exp_inv, mol_starts,
                                                params, out);
    pack_kernel<<<(N + BLK - 1) / BLK, BLK, 0, stream>>>(xyz, z, mol_starts, M, N,
                                                         pack);
    nr_main_kernel<<<NBLK, BLK, 0, stream>>>(nbrs, offsets, pack,
                                             params, out, E, M);
}